// Round 20
// baseline (175.368 us; speedup 1.0000x reference)
//
#include <hip/hip_runtime.h>

typedef __bf16 bf16x8 __attribute__((ext_vector_type(8)));
typedef float f32x4 __attribute__((ext_vector_type(4)));
typedef float f32x16 __attribute__((ext_vector_type(16)));
typedef int i32x4 __attribute__((ext_vector_type(4)));
typedef unsigned short u16x4 __attribute__((ext_vector_type(4)));

#define S_TOK 9216
#define LOG2E 1.44269504088896340736f
#define SCALE_Q (0.125f * LOG2E)

__device__ inline unsigned short f2bf(float f) {
    unsigned int u = __builtin_bit_cast(unsigned int, f);
    return (unsigned short)((u + 0x7fffu + ((u >> 16) & 1u)) >> 16);
}

__device__ inline unsigned int cvt_pk_bf16(float lo, float hi) {
    unsigned int r;
    asm("v_cvt_pk_bf16_f32 %0, %1, %2" : "=v"(r) : "v"(lo), "v"(hi));
    return r;
}

// v_permlane32_swap_b32 a, b : a[32:63] <-> b[0:31]
__device__ inline void permswap(unsigned int& a, unsigned int& b) {
    asm("v_permlane32_swap_b32 %0, %1" : "+v"(a), "+v"(b));
}

__device__ inline f32x4 MFMA(bf16x8 a, bf16x8 b, f32x4 c) {
    return __builtin_amdgcn_mfma_f32_16x16x32_bf16(a, b, c, 0, 0, 0);
}
__device__ inline f32x16 MFMA32(bf16x8 a, bf16x8 b, f32x16 c) {
    return __builtin_amdgcn_mfma_f32_32x32x16_bf16(a, b, c, 0, 0, 0);
}

// 16B-chunk swizzle for [rows][64]-bf16 LDS tiles (proven r8/r10)
__device__ inline int swz(int row, int c) {
    return ((c + (row >> 3)) & 7) ^ (row & 7);
}
__device__ inline bf16x8 load_frag(const unsigned short* lds, int outer, int kbase) {
    int lane = threadIdx.x & 63;
    int row = outer + (lane & 15);
    int cc = swz(row, (kbase >> 3) + (lane >> 4));
    return *reinterpret_cast<const bf16x8*>(lds + row * 64 + cc * 8);
}
__device__ inline bf16x8 load_frag32(const unsigned short* lds, int outer, int kbase) {
    int lane = threadIdx.x & 63;
    int row = outer + (lane & 31);
    int cc = swz(row, (kbase >> 3) + (lane >> 5));
    return *reinterpret_cast<const bf16x8*>(lds + row * 64 + cc * 8);
}
__device__ inline void stage_tile(unsigned short* lds, const unsigned short* src,
                                  int stride, int nrows) {
    for (int id = threadIdx.x; id < nrows * 8; id += 256) {
        int row = id >> 3, cc = id & 7;
        i32x4 v = *reinterpret_cast<const i32x4*>(src + row * stride + cc * 8);
        *reinterpret_cast<i32x4*>(lds + row * 64 + swz(row, cc) * 8) = v;
    }
}

// zero the f32 accumulators (O + l) each launch (atomics accumulate)
__global__ __launch_bounds__(256) void zero_f32(float* __restrict__ p, int n4) {
    f32x4 z = {0.f, 0.f, 0.f, 0.f};
    for (int i = blockIdx.x * 256 + threadIdx.x; i < n4; i += gridDim.x * 256)
        reinterpret_cast<f32x4*>(p)[i] = z;
}

// ---------------- GroupNorm ----------------
__global__ __launch_bounds__(256) void gn_stats_part(const float* __restrict__ x,
                                                     float* __restrict__ part) {
    int c = blockIdx.x;
    const f32x4* p = reinterpret_cast<const f32x4*>(x + c * S_TOK);
    float s = 0.f, ss = 0.f;
    for (int i = threadIdx.x; i < 2304; i += 256) {
        f32x4 v = p[i];
        s += v[0] + v[1] + v[2] + v[3];
        ss += v[0] * v[0] + v[1] * v[1] + v[2] * v[2] + v[3] * v[3];
    }
#pragma unroll
    for (int off = 1; off < 64; off <<= 1) {
        s += __shfl_xor(s, off);
        ss += __shfl_xor(ss, off);
    }
    __shared__ float rs[4], rss[4];
    int wave = threadIdx.x >> 6;
    if ((threadIdx.x & 63) == 0) { rs[wave] = s; rss[wave] = ss; }
    __syncthreads();
    if (threadIdx.x == 0) {
        part[c] = rs[0] + rs[1] + rs[2] + rs[3];
        part[256 + c] = rss[0] + rss[1] + rss[2] + rss[3];
    }
}

__global__ __launch_bounds__(256) void gn_apply(const float* __restrict__ x,
                                                const float* __restrict__ part,
                                                const float* __restrict__ nw,
                                                const float* __restrict__ nb,
                                                unsigned short* __restrict__ xf) {
    __shared__ float tl[64][65];
    __shared__ float gmean[8], grstd[8];
    int sb = blockIdx.x * 64, cb = blockIdx.y * 64;
    if (threadIdx.x < 8) {
        int g = (cb >> 3) + threadIdx.x;
        float s = 0.f, ss = 0.f;
#pragma unroll
        for (int i = 0; i < 8; ++i) { s += part[g * 8 + i]; ss += part[256 + g * 8 + i]; }
        float mean = s * (1.f / 73728.f);
        float var = ss * (1.f / 73728.f) - mean * mean;
        gmean[threadIdx.x] = mean;
        grstd[threadIdx.x] = rsqrtf(var + 1e-5f);
    }
    __syncthreads();
    for (int id = threadIdx.x; id < 1024; id += 256) {
        int cr = id >> 4;
        int sq = (id & 15) << 2;
        int c = cb + cr;
        f32x4 v = *reinterpret_cast<const f32x4*>(x + c * S_TOK + sb + sq);
        float mu = gmean[cr >> 3], rstd = grstd[cr >> 3];
        float wv = nw[c] * rstd;
        float bv = nb[c] - mu * wv;
#pragma unroll
        for (int j = 0; j < 4; ++j) tl[sq + j][cr] = v[j] * wv + bv;
    }
    __syncthreads();
    for (int id = threadIdx.x; id < 1024; id += 256) {
        int sr = id >> 4;
        int cq = (id & 15) << 2;
        u16x4 o;
#pragma unroll
        for (int j = 0; j < 4; ++j) o[j] = f2bf(tl[sr][cq + j]);
        *reinterpret_cast<u16x4*>(xf + (sb + sr) * 256 + cb + cq) = o;
    }
}

// both weight matrices -> bf16 in one launch (projw contiguous after qkvw in ws)
__global__ __launch_bounds__(256) void conv_both(const float* __restrict__ qkvw_in,
                                                 const float* __restrict__ projw_in,
                                                 unsigned short* __restrict__ out) {
    int i = blockIdx.x * 256 + threadIdx.x;  // 1024*256 total
    float v;
    if (i < 768 * 256) v = qkvw_in[i] * ((i < 256 * 256) ? SCALE_Q : 1.0f);
    else v = projw_in[i - 768 * 256];
    out[i] = f2bf(v);
}

// ---------------- QKV GEMM: C[m][n] = sum_k A[m][k]*B[n][k]
__global__ __launch_bounds__(256) void gemm_qkv(const unsigned short* __restrict__ A,
                                                const unsigned short* __restrict__ B,
                                                const float* __restrict__ bias,
                                                unsigned short* __restrict__ q_out,
                                                unsigned short* __restrict__ k_out,
                                                unsigned short* __restrict__ vT_out) {
    __shared__ alignas(16) unsigned short As[128 * 64];
    __shared__ alignas(16) unsigned short Bs[128 * 64];
    int mb = blockIdx.x, nb = blockIdx.y;
    int wave = threadIdx.x >> 6, lane = threadIdx.x & 63;
    int wm = wave >> 1, wn = wave & 1;
    f32x4 zero = {0.f, 0.f, 0.f, 0.f};
    f32x4 acc[4][4];
    for (int i = 0; i < 4; ++i)
        for (int j = 0; j < 4; ++j) acc[i][j] = zero;
    for (int ks = 0; ks < 4; ++ks) {
        __syncthreads();
        stage_tile(As, A + (mb * 128) * 256 + ks * 64, 256, 128);
        stage_tile(Bs, B + (nb * 128) * 256 + ks * 64, 256, 128);
        __syncthreads();
#pragma unroll
        for (int kk = 0; kk < 2; ++kk) {
            bf16x8 af[4], bfr[4];
#pragma unroll
            for (int mt = 0; mt < 4; ++mt) af[mt] = load_frag(As, wm * 64 + mt * 16, kk * 32);
#pragma unroll
            for (int nt = 0; nt < 4; ++nt) bfr[nt] = load_frag(Bs, wn * 64 + nt * 16, kk * 32);
#pragma unroll
            for (int mt = 0; mt < 4; ++mt)
#pragma unroll
                for (int nt = 0; nt < 4; ++nt)
                    acc[mt][nt] = MFMA(af[mt], bfr[nt], acc[mt][nt]);
        }
    }
    int r0 = (lane >> 4) << 2;
    int cl = lane & 15;
#pragma unroll
    for (int mt = 0; mt < 4; ++mt) {
#pragma unroll
        for (int nt = 0; nt < 4; ++nt) {
            int m = mb * 128 + wm * 64 + mt * 16 + r0;
            int n = nb * 128 + wn * 64 + nt * 16 + cl;
            float bv = bias[n] * ((n < 256) ? SCALE_Q : 1.0f);
            if (n < 256) {
#pragma unroll
                for (int r = 0; r < 4; ++r)
                    q_out[(m + r) * 256 + n] = f2bf(acc[mt][nt][r] + bv);
            } else if (n < 512) {
#pragma unroll
                for (int r = 0; r < 4; ++r)
                    k_out[(m + r) * 256 + (n - 256)] = f2bf(acc[mt][nt][r] + bv);
            } else {
                u16x4 o;
#pragma unroll
                for (int r = 0; r < 4; ++r) o[r] = f2bf(acc[mt][nt][r] + bv);
                *reinterpret_cast<u16x4*>(vT_out + (n - 512) * S_TOK + m) = o;
            }
        }
    }
}

// ---------------- proj GEMM: A = O/l normalized on the fly (head = ks) ----------
__global__ __launch_bounds__(256) void gemm_proj(const float* __restrict__ Of,
                                                 const float* __restrict__ lsum,
                                                 const unsigned short* __restrict__ Bw,
                                                 const float* __restrict__ bias,
                                                 const float* __restrict__ xres,
                                                 float* __restrict__ out) {
    __shared__ alignas(16) unsigned short As[128 * 64];
    __shared__ alignas(16) unsigned short Bs[128 * 64];
    int mb = blockIdx.x, nb = blockIdx.y;
    int wave = threadIdx.x >> 6, lane = threadIdx.x & 63;
    int wm = wave >> 1, wn = wave & 1;
    f32x4 zero = {0.f, 0.f, 0.f, 0.f};
    f32x4 acc[4][4];
    for (int i = 0; i < 4; ++i)
        for (int j = 0; j < 4; ++j) acc[i][j] = zero;
    for (int ks = 0; ks < 4; ++ks) {
        __syncthreads();
        // stage A: token rows, channels ks*64 + cc*8 (+j) -> head = ks
        for (int id = threadIdx.x; id < 1024; id += 256) {
            int row = id >> 3, cc = id & 7;
            int s = mb * 128 + row;
            const float* src = Of + s * 256 + ks * 64 + cc * 8;
            f32x4 a = *reinterpret_cast<const f32x4*>(src);
            f32x4 b = *reinterpret_cast<const f32x4*>(src + 4);
            float inv = 1.f / lsum[ks * S_TOK + s];
            i32x4 w;
            w[0] = (int)cvt_pk_bf16(a[0] * inv, a[1] * inv);
            w[1] = (int)cvt_pk_bf16(a[2] * inv, a[3] * inv);
            w[2] = (int)cvt_pk_bf16(b[0] * inv, b[1] * inv);
            w[3] = (int)cvt_pk_bf16(b[2] * inv, b[3] * inv);
            *reinterpret_cast<i32x4*>(As + row * 64 + swz(row, cc) * 8) = w;
        }
        stage_tile(Bs, Bw + (nb * 128) * 256 + ks * 64, 256, 128);
        __syncthreads();
#pragma unroll
        for (int kk = 0; kk < 2; ++kk) {
            bf16x8 af[4], bfr[4];
#pragma unroll
            for (int mt = 0; mt < 4; ++mt) af[mt] = load_frag(As, wm * 64 + mt * 16, kk * 32);
#pragma unroll
            for (int nt = 0; nt < 4; ++nt) bfr[nt] = load_frag(Bs, wn * 64 + nt * 16, kk * 32);
#pragma unroll
            for (int mt = 0; mt < 4; ++mt)
#pragma unroll
                for (int nt = 0; nt < 4; ++nt)
                    acc[mt][nt] = MFMA(af[mt], bfr[nt], acc[mt][nt]);
        }
    }
    int r0 = (lane >> 4) << 2;
    int cl = lane & 15;
#pragma unroll
    for (int mt = 0; mt < 4; ++mt) {
#pragma unroll
        for (int nt = 0; nt < 4; ++nt) {
            int m = mb * 128 + wm * 64 + mt * 16 + r0;
            int n = nb * 128 + wn * 64 + nt * 16 + cl;
            float bv = bias[n];
            f32x4 xr = *reinterpret_cast<const f32x4*>(xres + n * S_TOK + m);
            f32x4 o;
#pragma unroll
            for (int r = 0; r < 4; ++r) o[r] = acc[mt][nt][r] + bv + xr[r];
            *reinterpret_cast<f32x4*>(out + n * S_TOK + m) = o;
        }
    }
}

// ---------------- Flash attention: 256q blocks, atomic f32 O/l accumulation ------
struct StageRegs { i32x4 k0, k1, v0, v1; };

__device__ inline StageRegs load_stage(const unsigned short* ksrc, const unsigned short* vsrc) {
    int tid = threadIdx.x;
    int row = tid >> 3, cc = tid & 7;
    StageRegs r;
    r.k0 = *reinterpret_cast<const i32x4*>(ksrc + row * 256 + cc * 8);
    r.k1 = *reinterpret_cast<const i32x4*>(ksrc + (row + 32) * 256 + cc * 8);
    r.v0 = *reinterpret_cast<const i32x4*>(vsrc + row * S_TOK + cc * 8);
    r.v1 = *reinterpret_cast<const i32x4*>(vsrc + (row + 32) * S_TOK + cc * 8);
    return r;
}

__device__ inline void store_stage(unsigned short* K, unsigned short* V, StageRegs r) {
    int tid = threadIdx.x;
    int row = tid >> 3, cc = tid & 7;
    *reinterpret_cast<i32x4*>(K + row * 64 + swz(row, cc) * 8) = r.k0;
    *reinterpret_cast<i32x4*>(K + (row + 32) * 64 + swz(row + 32, cc) * 8) = r.k1;
    *reinterpret_cast<i32x4*>(V + row * 64 + swz(row, cc) * 8) = r.v0;
    *reinterpret_cast<i32x4*>(V + (row + 32) * 64 + swz(row + 32, cc) * 8) = r.v1;
}

// build PV A-fragment from 8 scores; accumulate unrounded exp-sum into lrun
__device__ inline bf16x8 mkpa(const f32x16& sc, int b, float& lrun) {
    float E0 = __builtin_amdgcn_exp2f(sc[b + 0]);
    float E1 = __builtin_amdgcn_exp2f(sc[b + 1]);
    float E2 = __builtin_amdgcn_exp2f(sc[b + 2]);
    float E3 = __builtin_amdgcn_exp2f(sc[b + 3]);
    float E4 = __builtin_amdgcn_exp2f(sc[b + 4]);
    float E5 = __builtin_amdgcn_exp2f(sc[b + 5]);
    float E6 = __builtin_amdgcn_exp2f(sc[b + 6]);
    float E7 = __builtin_amdgcn_exp2f(sc[b + 7]);
    lrun += ((E0 + E1) + (E2 + E3)) + ((E4 + E5) + (E6 + E7));
    unsigned int w0 = cvt_pk_bf16(E0, E1);
    unsigned int w1 = cvt_pk_bf16(E2, E3);
    unsigned int w2 = cvt_pk_bf16(E4, E5);
    unsigned int w3 = cvt_pk_bf16(E6, E7);
    permswap(w0, w2);
    permswap(w1, w3);
    i32x4 w;
    w[0] = (int)w0; w[1] = (int)w1; w[2] = (int)w2; w[3] = (int)w3;
    return __builtin_bit_cast(bf16x8, w);
}

template <int NC>
__global__ __launch_bounds__(256) void attn(const unsigned short* __restrict__ qb,
                                            const unsigned short* __restrict__ kb,
                                            const unsigned short* __restrict__ vT,
                                            float* __restrict__ Of,
                                            float* __restrict__ lsum) {
    __shared__ alignas(16) unsigned short LDS[4 * 4096];  // Ks0|Ks1|Vs0|Vs1 (32KB)
    unsigned short* Ks0 = LDS;
    unsigned short* Ks1 = LDS + 4096;
    unsigned short* Vs0 = LDS + 8192;
    unsigned short* Vs1 = LDS + 12288;
    constexpr int NS0 = 96 / NC, NS1 = 112 / NC, NS2 = 48 / NC;
    constexpr int B0 = 16 * NS0, B1 = B0 + 16 * NS1, NB = B1 + 4 * NS2;
    static_assert(NC % 2 == 0 && NC >= 4, "NC even");

    int bx = blockIdx.x;
    int head = bx / NB;
    int r = bx % NB;
    int tile, seg, qi;
    if (r < B0)      { tile = 0; seg = r >> 4; qi = r & 15; }
    else if (r < B1) { int t = r - B0; tile = 1; seg = t >> 4; qi = t & 15; }
    else             { int t = r - B1; tile = 2; seg = t >> 2; qi = t & 3; }
    int qs0 = (tile == 0) ? 0 : (tile == 1 ? 4096 : 8192);
    int kv0 = (tile == 0) ? 0 : (tile == 1 ? 2048 : 6144);
    int qstart = qs0 + qi * 256;
    int c0 = seg * NC;
    int wave = threadIdx.x >> 6, lane = threadIdx.x & 63;
    int l31 = lane & 31, h = lane >> 5;

    // stage all 256 Q rows through the 32KB buffer, hoist 8 fragments (2 subtiles)
    stage_tile(LDS, qb + qstart * 256 + head * 64, 256, 256);
    __syncthreads();
    bf16x8 qfA[4], qfB[4];
#pragma unroll
    for (int s = 0; s < 4; ++s) {
        qfA[s] = load_frag32(LDS, wave * 64, s * 16);
        qfB[s] = load_frag32(LDS, wave * 64 + 32, s * 16);
    }
    __syncthreads();

    f32x16 oA0, oA1, oB0, oB1;
#pragma unroll
    for (int i = 0; i < 16; ++i) { oA0[i] = 0.f; oA1[i] = 0.f; oB0[i] = 0.f; oB1[i] = 0.f; }
    float lA = 0.f, lB = 0.f;

    const unsigned short* kbase = kb + kv0 * 256 + head * 64;
    const unsigned short* vbase = vT + head * 64 * S_TOK + kv0;

    auto compute = [&](const unsigned short* Kp, const unsigned short* Vp) {
        __builtin_amdgcn_s_setprio(1);
#pragma unroll
        for (int half = 0; half < 2; ++half) {
            f32x16 sc0, sc1;
#pragma unroll
            for (int i = 0; i < 16; ++i) { sc0[i] = 0.f; sc1[i] = 0.f; }
#pragma unroll
            for (int s = 0; s < 4; ++s) {
                bf16x8 kf = load_frag32(Kp, half * 32, s * 16);
                sc0 = MFMA32(kf, qfA[s], sc0);
                sc1 = MFMA32(kf, qfB[s], sc1);
            }
#pragma unroll
            for (int sl = 0; sl < 2; ++sl) {
                bf16x8 paA = mkpa(sc0, 8 * sl, lA);
                bf16x8 paB = mkpa(sc1, 8 * sl, lB);
                int kvb = (half * 2 + sl) * 16;
                bf16x8 v0 = load_frag32(Vp, 0, kvb);
                bf16x8 v1 = load_frag32(Vp, 32, kvb);
                oA0 = MFMA32(paA, v0, oA0);
                oA1 = MFMA32(paA, v1, oA1);
                oB0 = MFMA32(paB, v0, oB0);
                oB1 = MFMA32(paB, v1, oB1);
            }
        }
        __builtin_amdgcn_s_setprio(0);
    };

    // prologue: chunk c0 -> buf0; prefetch c0+1
    StageRegs Ra = load_stage(kbase + c0 * (64 * 256), vbase + c0 * 64);
    store_stage(Ks0, Vs0, Ra);
    Ra = load_stage(kbase + (c0 + 1) * (64 * 256), vbase + (c0 + 1) * 64);
    __syncthreads();

#pragma unroll
    for (int k = 0; k < NC; ++k) {
        const unsigned short* Kp = (k & 1) ? Ks1 : Ks0;
        const unsigned short* Vp = (k & 1) ? Vs1 : Vs0;
        if (k + 1 < NC) {
            store_stage((k & 1) ? Ks0 : Ks1, (k & 1) ? Vs0 : Vs1, Ra);
            if (k + 2 < NC)
                Ra = load_stage(kbase + (c0 + k + 2) * (64 * 256), vbase + (c0 + k + 2) * 64);
        }
        compute(Kp, Vp);
        __syncthreads();
    }

    // epilogue: atomic f32 accumulation of unnormalized O and l
#pragma unroll
    for (int reg = 0; reg < 16; ++reg) {
        int qloc = (reg & 3) + 8 * (reg >> 2) + 4 * h;
        int sA = qstart + wave * 64 + qloc;
        int sB = sA + 32;
        atomicAdd(&Of[sA * 256 + head * 64 + l31], oA0[reg]);
        atomicAdd(&Of[sA * 256 + head * 64 + 32 + l31], oA1[reg]);
        atomicAdd(&Of[sB * 256 + head * 64 + l31], oB0[reg]);
        atomicAdd(&Of[sB * 256 + head * 64 + 32 + l31], oB1[reg]);
    }
    float lfA = lA + __shfl_xor(lA, 32);
    float lfB = lB + __shfl_xor(lB, 32);
    if (h == 0) {
        int sA = qstart + wave * 64 + l31;
        atomicAdd(&lsum[head * S_TOK + sA], lfA);
        atomicAdd(&lsum[head * S_TOK + sA + 32], lfB);
    }
}

extern "C" void kernel_launch(void* const* d_in, const int* in_sizes, int n_in,
                              void* d_out, int out_size, void* d_ws, size_t ws_size,
                              hipStream_t stream) {
    const float* x      = (const float*)d_in[0];
    const float* norm_w = (const float*)d_in[1];
    const float* norm_b = (const float*)d_in[2];
    const float* qkv_w  = (const float*)d_in[3];
    const float* qkv_b  = (const float*)d_in[4];
    const float* proj_w = (const float*)d_in[5];
    const float* proj_b = (const float*)d_in[6];
    float* outp = (float*)d_out;

    char* wsb = (char*)d_ws;
    float* part = (float*)wsb;                                    // 512 f32
    unsigned short* xf    = (unsigned short*)(wsb + 2048);        // [9216][256] bf16
    unsigned short* qkvw  = xf + 9216 * 256;                      // [768][256]
    unsigned short* projw = qkvw + 768 * 256;                     // [256][256]
    unsigned short* qbuf  = projw + 256 * 256;                    // [9216][256]
    unsigned short* kbuf  = qbuf + 9216 * 256;                    // [9216][256]
    unsigned short* vTbuf = kbuf + 9216 * 256;                    // [256][9216]
    float* Of   = (float*)(vTbuf + 256 * 9216);                   // [9216][256] f32
    float* lsum = Of + 9216 * 256;                                // [4][9216] f32

    int n4 = (9216 * 256 + 4 * S_TOK) / 4;
    zero_f32<<<dim3(1024), dim3(256), 0, stream>>>(Of, n4);
    gn_stats_part<<<dim3(256), dim3(256), 0, stream>>>(x, part);
    gn_apply<<<dim3(144, 4), dim3(256), 0, stream>>>(x, part, norm_w, norm_b, xf);
    conv_both<<<dim3(1024), dim3(256), 0, stream>>>(qkv_w, proj_w, qkvw);
    gemm_qkv<<<dim3(72, 6), dim3(256), 0, stream>>>(xf, qkvw, qkv_b, qbuf, kbuf, vTbuf);
    attn<8><<<dim3(4 * 440), dim3(256), 0, stream>>>(qbuf, kbuf, vTbuf, Of, lsum);
    gemm_proj<<<dim3(72, 2), dim3(256), 0, stream>>>(Of, lsum, projw, proj_b, x, outp);
}

// Round 22
// 138.055 us; speedup vs baseline: 1.2703x; 1.2703x over previous
//
#include <hip/hip_runtime.h>

typedef __bf16 bf16x8 __attribute__((ext_vector_type(8)));
typedef float f32x4 __attribute__((ext_vector_type(4)));
typedef float f32x16 __attribute__((ext_vector_type(16)));
typedef int i32x4 __attribute__((ext_vector_type(4)));
typedef unsigned short u16x4 __attribute__((ext_vector_type(4)));

#define S_TOK 9216
#define LOG2E 1.44269504088896340736f
#define SCALE_Q (0.125f * LOG2E)

__device__ inline unsigned short f2bf(float f) {
    unsigned int u = __builtin_bit_cast(unsigned int, f);
    return (unsigned short)((u + 0x7fffu + ((u >> 16) & 1u)) >> 16);
}

__device__ inline unsigned int cvt_pk_bf16(float lo, float hi) {
    unsigned int r;
    asm("v_cvt_pk_bf16_f32 %0, %1, %2" : "=v"(r) : "v"(lo), "v"(hi));
    return r;
}

// v_permlane32_swap_b32 a, b : a[32:63] <-> b[0:31]
__device__ inline void permswap(unsigned int& a, unsigned int& b) {
    asm("v_permlane32_swap_b32 %0, %1" : "+v"(a), "+v"(b));
}

__device__ inline f32x4 MFMA(bf16x8 a, bf16x8 b, f32x4 c) {
    return __builtin_amdgcn_mfma_f32_16x16x32_bf16(a, b, c, 0, 0, 0);
}
__device__ inline f32x16 MFMA32(bf16x8 a, bf16x8 b, f32x16 c) {
    return __builtin_amdgcn_mfma_f32_32x32x16_bf16(a, b, c, 0, 0, 0);
}

// 16B-chunk swizzle for [rows][64]-bf16 LDS tiles (proven r8/r10)
__device__ inline int swz(int row, int c) {
    return ((c + (row >> 3)) & 7) ^ (row & 7);
}
__device__ inline bf16x8 load_frag(const unsigned short* lds, int outer, int kbase) {
    int lane = threadIdx.x & 63;
    int row = outer + (lane & 15);
    int cc = swz(row, (kbase >> 3) + (lane >> 4));
    return *reinterpret_cast<const bf16x8*>(lds + row * 64 + cc * 8);
}
__device__ inline bf16x8 load_frag32(const unsigned short* lds, int outer, int kbase) {
    int lane = threadIdx.x & 63;
    int row = outer + (lane & 31);
    int cc = swz(row, (kbase >> 3) + (lane >> 5));
    return *reinterpret_cast<const bf16x8*>(lds + row * 64 + cc * 8);
}
__device__ inline void stage_tile(unsigned short* lds, const unsigned short* src,
                                  int stride, int nrows) {
    for (int id = threadIdx.x; id < nrows * 8; id += 256) {
        int row = id >> 3, cc = id & 7;
        i32x4 v = *reinterpret_cast<const i32x4*>(src + row * stride + cc * 8);
        *reinterpret_cast<i32x4*>(lds + row * 64 + swz(row, cc) * 8) = v;
    }
}

// ---------------- GroupNorm ----------------
__global__ __launch_bounds__(256) void gn_stats_part(const float* __restrict__ x,
                                                     float* __restrict__ part) {
    int c = blockIdx.x;
    const f32x4* p = reinterpret_cast<const f32x4*>(x + c * S_TOK);
    float s = 0.f, ss = 0.f;
    for (int i = threadIdx.x; i < 2304; i += 256) {
        f32x4 v = p[i];
        s += v[0] + v[1] + v[2] + v[3];
        ss += v[0] * v[0] + v[1] * v[1] + v[2] * v[2] + v[3] * v[3];
    }
#pragma unroll
    for (int off = 1; off < 64; off <<= 1) {
        s += __shfl_xor(s, off);
        ss += __shfl_xor(ss, off);
    }
    __shared__ float rs[4], rss[4];
    int wave = threadIdx.x >> 6;
    if ((threadIdx.x & 63) == 0) { rs[wave] = s; rss[wave] = ss; }
    __syncthreads();
    if (threadIdx.x == 0) {
        part[c] = rs[0] + rs[1] + rs[2] + rs[3];
        part[256 + c] = rss[0] + rss[1] + rss[2] + rss[3];
    }
}

__global__ __launch_bounds__(256) void gn_apply(const float* __restrict__ x,
                                                const float* __restrict__ part,
                                                const float* __restrict__ nw,
                                                const float* __restrict__ nb,
                                                unsigned short* __restrict__ xf) {
    __shared__ float tl[64][65];
    __shared__ float gmean[8], grstd[8];
    int sb = blockIdx.x * 64, cb = blockIdx.y * 64;
    if (threadIdx.x < 8) {
        int g = (cb >> 3) + threadIdx.x;
        float s = 0.f, ss = 0.f;
#pragma unroll
        for (int i = 0; i < 8; ++i) { s += part[g * 8 + i]; ss += part[256 + g * 8 + i]; }
        float mean = s * (1.f / 73728.f);
        float var = ss * (1.f / 73728.f) - mean * mean;
        gmean[threadIdx.x] = mean;
        grstd[threadIdx.x] = rsqrtf(var + 1e-5f);
    }
    __syncthreads();
    for (int id = threadIdx.x; id < 1024; id += 256) {
        int cr = id >> 4;
        int sq = (id & 15) << 2;
        int c = cb + cr;
        f32x4 v = *reinterpret_cast<const f32x4*>(x + c * S_TOK + sb + sq);
        float mu = gmean[cr >> 3], rstd = grstd[cr >> 3];
        float wv = nw[c] * rstd;
        float bv = nb[c] - mu * wv;
#pragma unroll
        for (int j = 0; j < 4; ++j) tl[sq + j][cr] = v[j] * wv + bv;
    }
    __syncthreads();
    for (int id = threadIdx.x; id < 1024; id += 256) {
        int sr = id >> 4;
        int cq = (id & 15) << 2;
        u16x4 o;
#pragma unroll
        for (int j = 0; j < 4; ++j) o[j] = f2bf(tl[sr][cq + j]);
        *reinterpret_cast<u16x4*>(xf + (sb + sr) * 256 + cb + cq) = o;
    }
}

// both weight matrices -> bf16 in one launch (projw contiguous after qkvw in ws)
__global__ __launch_bounds__(256) void conv_both(const float* __restrict__ qkvw_in,
                                                 const float* __restrict__ projw_in,
                                                 unsigned short* __restrict__ out) {
    int i = blockIdx.x * 256 + threadIdx.x;  // 1024*256 total
    float v;
    if (i < 768 * 256) v = qkvw_in[i] * ((i < 256 * 256) ? SCALE_Q : 1.0f);
    else v = projw_in[i - 768 * 256];
    out[i] = f2bf(v);
}

// ---------------- GEMM: C[m][n] = sum_k A[m][k]*B[n][k]
template <int MODE>
__global__ __launch_bounds__(256) void gemm_bt(const unsigned short* __restrict__ A,
                                               const unsigned short* __restrict__ B,
                                               const float* __restrict__ bias,
                                               unsigned short* __restrict__ q_out,
                                               unsigned short* __restrict__ k_out,
                                               unsigned short* __restrict__ vT_out,
                                               const float* __restrict__ xres,
                                               float* __restrict__ out) {
    __shared__ alignas(16) unsigned short As[128 * 64];
    __shared__ alignas(16) unsigned short Bs[128 * 64];
    int mb = blockIdx.x, nb = blockIdx.y;
    int wave = threadIdx.x >> 6, lane = threadIdx.x & 63;
    int wm = wave >> 1, wn = wave & 1;
    f32x4 zero = {0.f, 0.f, 0.f, 0.f};
    f32x4 acc[4][4];
    for (int i = 0; i < 4; ++i)
        for (int j = 0; j < 4; ++j) acc[i][j] = zero;
    for (int ks = 0; ks < 4; ++ks) {
        __syncthreads();
        stage_tile(As, A + (mb * 128) * 256 + ks * 64, 256, 128);
        stage_tile(Bs, B + (nb * 128) * 256 + ks * 64, 256, 128);
        __syncthreads();
#pragma unroll
        for (int kk = 0; kk < 2; ++kk) {
            bf16x8 af[4], bfr[4];
#pragma unroll
            for (int mt = 0; mt < 4; ++mt) af[mt] = load_frag(As, wm * 64 + mt * 16, kk * 32);
#pragma unroll
            for (int nt = 0; nt < 4; ++nt) bfr[nt] = load_frag(Bs, wn * 64 + nt * 16, kk * 32);
#pragma unroll
            for (int mt = 0; mt < 4; ++mt)
#pragma unroll
                for (int nt = 0; nt < 4; ++nt)
                    acc[mt][nt] = MFMA(af[mt], bfr[nt], acc[mt][nt]);
        }
    }
    int r0 = (lane >> 4) << 2;
    int cl = lane & 15;
#pragma unroll
    for (int mt = 0; mt < 4; ++mt) {
#pragma unroll
        for (int nt = 0; nt < 4; ++nt) {
            int m = mb * 128 + wm * 64 + mt * 16 + r0;
            int n = nb * 128 + wn * 64 + nt * 16 + cl;
            if (MODE == 0) {
                float bv = bias[n] * ((n < 256) ? SCALE_Q : 1.0f);
                if (n < 256) {
#pragma unroll
                    for (int r = 0; r < 4; ++r)
                        q_out[(m + r) * 256 + n] = f2bf(acc[mt][nt][r] + bv);
                } else if (n < 512) {
#pragma unroll
                    for (int r = 0; r < 4; ++r)
                        k_out[(m + r) * 256 + (n - 256)] = f2bf(acc[mt][nt][r] + bv);
                } else {
                    u16x4 o;
#pragma unroll
                    for (int r = 0; r < 4; ++r) o[r] = f2bf(acc[mt][nt][r] + bv);
                    *reinterpret_cast<u16x4*>(vT_out + (n - 512) * S_TOK + m) = o;
                }
            } else {
                float bv = bias[n];
                f32x4 xr = *reinterpret_cast<const f32x4*>(xres + n * S_TOK + m);
                f32x4 o;
#pragma unroll
                for (int r = 0; r < 4; ++r) o[r] = acc[mt][nt][r] + bv + xr[r];
                *reinterpret_cast<f32x4*>(out + n * S_TOK + m) = o;
            }
        }
    }
}

// ---------------- Flash attention: 256q blocks (4 waves x 64q), 32x32 MFMA --------
// K/V fragments feed both 32-q subtiles (r16). In-register l (r19): lane sums its
// unrounded E values instead of a ones-MFMA. bf16 Opart partials + combine
// (r20 showed f32 atomics cost +44us: WRITE_SIZE 58->114MB, uncoalesced RMW).
struct StageRegs { i32x4 k0, k1, v0, v1; };

__device__ inline StageRegs load_stage(const unsigned short* ksrc, const unsigned short* vsrc) {
    int tid = threadIdx.x;
    int row = tid >> 3, cc = tid & 7;
    StageRegs r;
    r.k0 = *reinterpret_cast<const i32x4*>(ksrc + row * 256 + cc * 8);
    r.k1 = *reinterpret_cast<const i32x4*>(ksrc + (row + 32) * 256 + cc * 8);
    r.v0 = *reinterpret_cast<const i32x4*>(vsrc + row * S_TOK + cc * 8);
    r.v1 = *reinterpret_cast<const i32x4*>(vsrc + (row + 32) * S_TOK + cc * 8);
    return r;
}

__device__ inline void store_stage(unsigned short* K, unsigned short* V, StageRegs r) {
    int tid = threadIdx.x;
    int row = tid >> 3, cc = tid & 7;
    *reinterpret_cast<i32x4*>(K + row * 64 + swz(row, cc) * 8) = r.k0;
    *reinterpret_cast<i32x4*>(K + (row + 32) * 64 + swz(row + 32, cc) * 8) = r.k1;
    *reinterpret_cast<i32x4*>(V + row * 64 + swz(row, cc) * 8) = r.v0;
    *reinterpret_cast<i32x4*>(V + (row + 32) * 64 + swz(row + 32, cc) * 8) = r.v1;
}

// build PV A-fragment from 8 scores; accumulate unrounded exp-sum into lrun
__device__ inline bf16x8 mkpa(const f32x16& sc, int b, float& lrun) {
    float E0 = __builtin_amdgcn_exp2f(sc[b + 0]);
    float E1 = __builtin_amdgcn_exp2f(sc[b + 1]);
    float E2 = __builtin_amdgcn_exp2f(sc[b + 2]);
    float E3 = __builtin_amdgcn_exp2f(sc[b + 3]);
    float E4 = __builtin_amdgcn_exp2f(sc[b + 4]);
    float E5 = __builtin_amdgcn_exp2f(sc[b + 5]);
    float E6 = __builtin_amdgcn_exp2f(sc[b + 6]);
    float E7 = __builtin_amdgcn_exp2f(sc[b + 7]);
    lrun += ((E0 + E1) + (E2 + E3)) + ((E4 + E5) + (E6 + E7));
    unsigned int w0 = cvt_pk_bf16(E0, E1);
    unsigned int w1 = cvt_pk_bf16(E2, E3);
    unsigned int w2 = cvt_pk_bf16(E4, E5);
    unsigned int w3 = cvt_pk_bf16(E6, E7);
    permswap(w0, w2);
    permswap(w1, w3);
    i32x4 w;
    w[0] = (int)w0; w[1] = (int)w1; w[2] = (int)w2; w[3] = (int)w3;
    return __builtin_bit_cast(bf16x8, w);
}

template <int NC>
__global__ __launch_bounds__(256) void attn(const unsigned short* __restrict__ qb,
                                            const unsigned short* __restrict__ kb,
                                            const unsigned short* __restrict__ vT,
                                            unsigned short* __restrict__ Opart,
                                            float* __restrict__ lpart) {
    __shared__ alignas(16) unsigned short LDS[4 * 4096];  // Ks0|Ks1|Vs0|Vs1 (32KB)
    unsigned short* Ks0 = LDS;
    unsigned short* Ks1 = LDS + 4096;
    unsigned short* Vs0 = LDS + 8192;
    unsigned short* Vs1 = LDS + 12288;
    constexpr int NS0 = 96 / NC, NS1 = 112 / NC, NS2 = 48 / NC;
    constexpr int B0 = 16 * NS0, B1 = B0 + 16 * NS1, NB = B1 + 4 * NS2;
    static_assert(NC % 2 == 0 && NC >= 4, "NC even");

    int bx = blockIdx.x;
    int head = bx / NB;
    int r = bx % NB;
    int tile, seg, qi;
    if (r < B0)      { tile = 0; seg = r >> 4; qi = r & 15; }
    else if (r < B1) { int t = r - B0; tile = 1; seg = t >> 4; qi = t & 15; }
    else             { int t = r - B1; tile = 2; seg = t >> 2; qi = t & 3; }
    int qs0 = (tile == 0) ? 0 : (tile == 1 ? 4096 : 8192);
    int kv0 = (tile == 0) ? 0 : (tile == 1 ? 2048 : 6144);
    int qstart = qs0 + qi * 256;
    int c0 = seg * NC;
    int wave = threadIdx.x >> 6, lane = threadIdx.x & 63;
    int l31 = lane & 31, h = lane >> 5;

    // stage all 256 Q rows through the 32KB buffer, hoist 8 fragments (2 subtiles)
    stage_tile(LDS, qb + qstart * 256 + head * 64, 256, 256);
    __syncthreads();
    bf16x8 qfA[4], qfB[4];
#pragma unroll
    for (int s = 0; s < 4; ++s) {
        qfA[s] = load_frag32(LDS, wave * 64, s * 16);
        qfB[s] = load_frag32(LDS, wave * 64 + 32, s * 16);
    }
    __syncthreads();

    f32x16 oA0, oA1, oB0, oB1;
#pragma unroll
    for (int i = 0; i < 16; ++i) { oA0[i] = 0.f; oA1[i] = 0.f; oB0[i] = 0.f; oB1[i] = 0.f; }
    float lA = 0.f, lB = 0.f;

    const unsigned short* kbase = kb + kv0 * 256 + head * 64;
    const unsigned short* vbase = vT + head * 64 * S_TOK + kv0;

    auto compute = [&](const unsigned short* Kp, const unsigned short* Vp) {
        __builtin_amdgcn_s_setprio(1);
#pragma unroll
        for (int half = 0; half < 2; ++half) {
            f32x16 sc0, sc1;
#pragma unroll
            for (int i = 0; i < 16; ++i) { sc0[i] = 0.f; sc1[i] = 0.f; }
#pragma unroll
            for (int s = 0; s < 4; ++s) {
                bf16x8 kf = load_frag32(Kp, half * 32, s * 16);
                sc0 = MFMA32(kf, qfA[s], sc0);
                sc1 = MFMA32(kf, qfB[s], sc1);
            }
#pragma unroll
            for (int sl = 0; sl < 2; ++sl) {
                bf16x8 paA = mkpa(sc0, 8 * sl, lA);
                bf16x8 paB = mkpa(sc1, 8 * sl, lB);
                int kvb = (half * 2 + sl) * 16;
                bf16x8 v0 = load_frag32(Vp, 0, kvb);
                bf16x8 v1 = load_frag32(Vp, 32, kvb);
                oA0 = MFMA32(paA, v0, oA0);
                oA1 = MFMA32(paA, v1, oA1);
                oB0 = MFMA32(paB, v0, oB0);
                oB1 = MFMA32(paB, v1, oB1);
            }
        }
        __builtin_amdgcn_s_setprio(0);
    };

    // prologue: chunk c0 -> buf0; prefetch c0+1
    StageRegs Ra = load_stage(kbase + c0 * (64 * 256), vbase + c0 * 64);
    store_stage(Ks0, Vs0, Ra);
    Ra = load_stage(kbase + (c0 + 1) * (64 * 256), vbase + (c0 + 1) * 64);
    __syncthreads();

#pragma unroll
    for (int k = 0; k < NC; ++k) {
        const unsigned short* Kp = (k & 1) ? Ks1 : Ks0;
        const unsigned short* Vp = (k & 1) ? Vs1 : Vs0;
        if (k + 1 < NC) {
            store_stage((k & 1) ? Ks0 : Ks1, (k & 1) ? Vs0 : Vs1, Ra);
            if (k + 2 < NC)
                Ra = load_stage(kbase + (c0 + k + 2) * (64 * 256), vbase + (c0 + k + 2) * 64);
        }
        compute(Kp, Vp);
        __syncthreads();
    }

    // epilogue: unnormalized O partials + l partials
    unsigned int obase = (unsigned int)seg * (S_TOK * 256);
#pragma unroll
    for (int reg = 0; reg < 16; ++reg) {
        int qloc = (reg & 3) + 8 * (reg >> 2) + 4 * h;
        int sA = qstart + wave * 64 + qloc;
        int sB = sA + 32;
        Opart[obase + sA * 256 + head * 64 + l31] =
            __builtin_bit_cast(unsigned short, (__bf16)oA0[reg]);
        Opart[obase + sA * 256 + head * 64 + 32 + l31] =
            __builtin_bit_cast(unsigned short, (__bf16)oA1[reg]);
        Opart[obase + sB * 256 + head * 64 + l31] =
            __builtin_bit_cast(unsigned short, (__bf16)oB0[reg]);
        Opart[obase + sB * 256 + head * 64 + 32 + l31] =
            __builtin_bit_cast(unsigned short, (__bf16)oB1[reg]);
    }
    float lfA = lA + __shfl_xor(lA, 32);
    float lfB = lB + __shfl_xor(lB, 32);
    if (h == 0) {
        int sA = qstart + wave * 64 + l31;
        lpart[(seg * 4 + head) * S_TOK + sA] = lfA;
        lpart[(seg * 4 + head) * S_TOK + sA + 32] = lfB;
    }
}

// combine: att[s][c] = (sum_slot O[slot][s][c]) / (sum_slot l[slot][head(c)][s])
template <int NC>
__global__ __launch_bounds__(256) void combine(const unsigned short* __restrict__ Op,
                                               const float* __restrict__ lp,
                                               unsigned short* __restrict__ att) {
    int idx = blockIdx.x * 256 + threadIdx.x;  // 9216*32
    int s = idx >> 5;
    int c0 = (idx & 31) << 3;
    int head = c0 >> 6;
    int nseg = (s < 4096) ? (96 / NC) : (s < 8192 ? (112 / NC) : (48 / NC));
    float acc[8] = {0.f, 0.f, 0.f, 0.f, 0.f, 0.f, 0.f, 0.f};
    float l = 0.f;
    for (int seg = 0; seg < nseg; ++seg) {
        i32x4 v = *reinterpret_cast<const i32x4*>(Op + (size_t)seg * (S_TOK * 256) + s * 256 + c0);
        const unsigned short* u = reinterpret_cast<const unsigned short*>(&v);
#pragma unroll
        for (int i = 0; i < 8; ++i)
            acc[i] += __builtin_bit_cast(float, ((unsigned int)u[i]) << 16);
        l += lp[(seg * 4 + head) * S_TOK + s];
    }
    float inv = 1.f / l;
    u16x4 o0, o1;
#pragma unroll
    for (int i = 0; i < 4; ++i) {
        o0[i] = f2bf(acc[i] * inv);
        o1[i] = f2bf(acc[4 + i] * inv);
    }
    unsigned short* dst = att + s * 256 + c0;
    *reinterpret_cast<u16x4*>(dst) = o0;
    *reinterpret_cast<u16x4*>(dst + 4) = o1;
}

extern "C" void kernel_launch(void* const* d_in, const int* in_sizes, int n_in,
                              void* d_out, int out_size, void* d_ws, size_t ws_size,
                              hipStream_t stream) {
    const float* x      = (const float*)d_in[0];
    const float* norm_w = (const float*)d_in[1];
    const float* norm_b = (const float*)d_in[2];
    const float* qkv_w  = (const float*)d_in[3];
    const float* qkv_b  = (const float*)d_in[4];
    const float* proj_w = (const float*)d_in[5];
    const float* proj_b = (const float*)d_in[6];
    float* outp = (float*)d_out;

    char* wsb = (char*)d_ws;
    float* part = (float*)wsb;                                    // 512 f32
    unsigned short* xf    = (unsigned short*)(wsb + 2048);        // [9216][256] bf16
    unsigned short* qkvw  = xf + 9216 * 256;                      // [768][256]
    unsigned short* projw = qkvw + 768 * 256;                     // [256][256]
    unsigned short* qbuf  = projw + 256 * 256;                    // [9216][256]
    unsigned short* kbuf  = qbuf + 9216 * 256;                    // [9216][256]
    unsigned short* vTbuf = kbuf + 9216 * 256;                    // [256][9216]
    unsigned short* Opart = vTbuf + 256 * 9216;                   // [MS][9216][256] bf16
    size_t fixed_bytes = 2048 + 2ull * 256 * (9216ull * 4 + 768 + 256);
    size_t need8 = fixed_bytes + 2ull * 14 * 9216 * 256 + 4ull * 14 * 4 * 9216;
    bool use8 = (ws_size >= need8);
    int MS = use8 ? 14 : 7;
    float* lpart = (float*)(Opart + (size_t)MS * 9216 * 256);     // [MS*4][9216] f32
    unsigned short* attb  = xf;  // alias: xf dead after QKV GEMM

    gn_stats_part<<<dim3(256), dim3(256), 0, stream>>>(x, part);
    gn_apply<<<dim3(144, 4), dim3(256), 0, stream>>>(x, part, norm_w, norm_b, xf);
    conv_both<<<dim3(1024), dim3(256), 0, stream>>>(qkv_w, proj_w, qkvw);
    gemm_bt<0><<<dim3(72, 6), dim3(256), 0, stream>>>(xf, qkvw, qkv_b,
                                                      qbuf, kbuf, vTbuf, nullptr, nullptr);
    if (use8) {
        attn<8><<<dim3(4 * 440), dim3(256), 0, stream>>>(qbuf, kbuf, vTbuf, Opart, lpart);
        combine<8><<<dim3(1152), dim3(256), 0, stream>>>(Opart, lpart, attb);
    } else {
        attn<16><<<dim3(4 * 220), dim3(256), 0, stream>>>(qbuf, kbuf, vTbuf, Opart, lpart);
        combine<16><<<dim3(1152), dim3(256), 0, stream>>>(Opart, lpart, attb);
    }
    gemm_bt<1><<<dim3(72, 2), dim3(256), 0, stream>>>(attb, projw, proj_b,
                                                      nullptr, nullptr, nullptr, x, outp);
}